// Round 11
// baseline (3285.681 us; speedup 1.0000x reference)
//
#include <hip/hip_runtime.h>
#include <hip/hip_fp16.h>

#define NN 100000
#define NE 3200000
#define NBIN 782   // ceil(NN/128) bins of 128 nodes
#define NBLK 256   // partition blocks
#define CHE 12500  // edges per partition block (NBLK*CHE == NE)

// ---------- fp16 pack/unpack helpers ----------
__device__ inline unsigned pkh(float a, float b) {
  __half2 h;
  h.x = __float2half(a);
  h.y = __float2half(b);
  unsigned u;
  __builtin_memcpy(&u, &h, 4);
  return u;
}
__device__ inline float2 uph(unsigned u) {
  __half2 h;
  __builtin_memcpy(&h, &u, 4);
  return __half22float2(h);
}
__device__ inline float h1f(unsigned short v) {
  __half h;
  __builtin_memcpy(&h, &v, 2);
  return __half2float(h);
}
__device__ inline unsigned short f1h(float f) {
  __half h = __float2half(f);
  unsigned short u;
  __builtin_memcpy(&u, &h, 2);
  return u;
}

// ============== bin partition (replaces per-node CSR entirely) ===============
// Phase H: per-block LDS histogram over 782 bins -> blkhist[block*NBIN+bin]
__global__ __launch_bounds__(256) void histk_kernel(const int* __restrict__ dst,
                                                    int* __restrict__ blkhist) {
  __shared__ int hist[NBIN];
  int tid = threadIdx.x;
  for (int i = tid; i < NBIN; i += 256) hist[i] = 0;
  __syncthreads();
  int c0 = blockIdx.x * CHE, c1 = c0 + CHE;
  for (int e = c0 + tid; e < c1; e += 256) atomicAdd(&hist[dst[e] >> 7], 1);
  __syncthreads();
  for (int i = tid; i < NBIN; i += 256)
    blkhist[blockIdx.x * NBIN + i] = hist[i];
}

// Phase S: single block. Per bin: prefix over blocks (in-place), bin totals ->
// exclusive scan -> binstart; add binstart into per-(block,bin) bases.
__global__ __launch_bounds__(1024) void scank_kernel(int* __restrict__ blkhist,
                                                     int* __restrict__ binstart) {
  __shared__ int tot[1024];
  int b = threadIdx.x;
  int running = 0;
  if (b < NBIN) {
    for (int blk = 0; blk < NBLK; blk++) {
      int v = blkhist[blk * NBIN + b];
      blkhist[blk * NBIN + b] = running;
      running += v;
    }
  }
  tot[b] = (b < NBIN) ? running : 0;
  __syncthreads();
  for (int off = 1; off < 1024; off <<= 1) {
    int v = tot[b];
    int u = (b >= off) ? tot[b - off] : 0;
    __syncthreads();
    tot[b] = v + u;
    __syncthreads();
  }
  int start = (b == 0) ? 0 : tot[b - 1];
  if (b < NBIN) {
    binstart[b] = start;
    for (int blk = 0; blk < NBLK; blk++) blkhist[blk * NBIN + b] += start;
  }
  if (b == 0) binstart[NBIN] = tot[1023];
}

// Phase P: scatter into bin-major staging. Offsets are PRIVATE LDS counters
// (no global atomic contention); per-(block,bin) runs ~16 edges sequential.
//   stageR[pos] = uint4{ pkh(ea0,ea1), pkh(ea2,ea3), pkh(ea4,ea5),
//                        f1h(ea6) | (dst&127)<<16 }
//   stageS[pos] = src
__global__ __launch_bounds__(256) void scatk_kernel(
    const int* __restrict__ src, const int* __restrict__ dst,
    const float* __restrict__ ea, const int* __restrict__ blkhist,
    uint4* __restrict__ stageR, int* __restrict__ stageS) {
  __shared__ int ofs[NBIN];
  int tid = threadIdx.x;
  for (int i = tid; i < NBIN; i += 256)
    ofs[i] = blkhist[blockIdx.x * NBIN + i];
  __syncthreads();
  int c0 = blockIdx.x * CHE, c1 = c0 + CHE;
  for (int e = c0 + tid; e < c1; e += 256) {
    int dn = dst[e];
    int sn = src[e];
    float av[7];
#pragma unroll
    for (int k = 0; k < 7; k++) av[k] = ea[e * 7 + k];
    int pos = atomicAdd(&ofs[dn >> 7], 1);
    uint4 r;
    r.x = pkh(av[0], av[1]);
    r.y = pkh(av[2], av[3]);
    r.z = pkh(av[4], av[5]);
    r.w = (unsigned)f1h(av[6]) | (((unsigned)dn & 127u) << 16);
    stageR[pos] = r;
    stageS[pos] = sn;
  }
}

// ====== layer 1: bin-per-block aggregation into LDS acc[128][2] ==============
__global__ __launch_bounds__(256) void gine2b_kernel(
    const int* __restrict__ binstart, const uint4* __restrict__ stageR,
    const int* __restrict__ stageS, const float* __restrict__ x,
    const float* __restrict__ elw, const float* __restrict__ elb,
    float* __restrict__ agg1) {
  __shared__ float acc[128][2];
  int tid = threadIdx.x;
  float w0[7], w1r[7];
#pragma unroll
  for (int k = 0; k < 7; k++) { w0[k] = elw[k * 2]; w1r[k] = elw[k * 2 + 1]; }
  float b0 = elb[0], b1 = elb[1];
  if (tid < 128) { acc[tid][0] = 0.f; acc[tid][1] = 0.f; }
  __syncthreads();
  int r0 = binstart[blockIdx.x], r1 = binstart[blockIdx.x + 1];
  for (int i = r0 + tid; i < r1; i += 256) {
    uint4 u = stageR[i];
    int sn = stageS[i];
    int ln = (int)((u.w >> 16) & 127u);
    float2 q0 = uph(u.x), q1 = uph(u.y), q2 = uph(u.z);
    float e6 = h1f((unsigned short)(u.w & 0xFFFFu));
    float m0 = b0, m1 = b1;
    m0 = fmaf(q0.x, w0[0], m0); m1 = fmaf(q0.x, w1r[0], m1);
    m0 = fmaf(q0.y, w0[1], m0); m1 = fmaf(q0.y, w1r[1], m1);
    m0 = fmaf(q1.x, w0[2], m0); m1 = fmaf(q1.x, w1r[2], m1);
    m0 = fmaf(q1.y, w0[3], m0); m1 = fmaf(q1.y, w1r[3], m1);
    m0 = fmaf(q2.x, w0[4], m0); m1 = fmaf(q2.x, w1r[4], m1);
    m0 = fmaf(q2.y, w0[5], m0); m1 = fmaf(q2.y, w1r[5], m1);
    m0 = fmaf(e6, w0[6], m0);   m1 = fmaf(e6, w1r[6], m1);
    m0 = fmaxf(m0 + x[sn * 2 + 0], 0.f);
    m1 = fmaxf(m1 + x[sn * 2 + 1], 0.f);
    atomicAdd(&acc[ln][0], m0);
    atomicAdd(&acc[ln][1], m1);
  }
  __syncthreads();
  int n = (blockIdx.x << 7) + tid;
  if (tid < 128 && n < NN) {
    agg1[n * 2 + 0] = acc[tid][0];
    agg1[n * 2 + 1] = acc[tid][1];
  }
}

#define PROJH(m, u) do { \
  float2 q0 = uph((u).x), q1 = uph((u).y), q2 = uph((u).z), q3 = uph((u).w); \
  m = bel; \
  m = fmaf(q0.x, wel[0], m); m = fmaf(q0.y, wel[1], m); \
  m = fmaf(q1.x, wel[2], m); m = fmaf(q1.y, wel[3], m); \
  m = fmaf(q2.x, wel[4], m); m = fmaf(q2.y, wel[5], m); \
  m = fmaf(q3.x, wel[6], m); } while (0)

// ====== layers 2/3: bin-per-block, LDS acc[128][64], continuous 4-deep
// gather pipeline over the bin's edge stream; fused h + w1 matmul + stats ====
__global__ __launch_bounds__(256) void gine64b_kernel(
    const int* __restrict__ binstart, const uint4* __restrict__ stageR,
    const int* __restrict__ stageS, const float* __restrict__ xin,
    const unsigned short* __restrict__ xh, const float* __restrict__ elw,
    const float* __restrict__ elb, const float* __restrict__ w1,
    const float* __restrict__ b1, const float* __restrict__ eps_p,
    float* __restrict__ tbuf, float* __restrict__ stats) {
  __shared__ float wl[64 * 64];      // 16KB
  __shared__ float acc[128][64];     // 32KB
  __shared__ float hb[4][64];
  __shared__ float red[256];
  int tid = threadIdx.x, lane = tid & 63, wv = tid >> 6;
  for (int i2 = tid; i2 < 64 * 64; i2 += 256) wl[i2] = w1[i2];
  float wel[7];
#pragma unroll
  for (int k = 0; k < 7; k++) wel[k] = elw[k * 64 + lane];
  float bel = elb[lane], b1c = b1[lane];
  float ep = 1.0f + *eps_p;
  for (int i2 = tid; i2 < 128 * 64; i2 += 256) ((float*)acc)[i2] = 0.f;
  __syncthreads();
  int r0 = binstart[blockIdx.x], r1 = binstart[blockIdx.x + 1];
  int len = r1 - r0;
  int per = (len + 3) >> 2;
  int lo = r0 + wv * per;
  int hi = lo + per < r1 ? lo + per : r1;
  if (lo > r1) lo = r1;
  const unsigned short* xl = xh + lane;
  int i = lo;
  if (hi - lo >= 4) {
    uint4 u0 = stageR[i], u1 = stageR[i + 1], u2 = stageR[i + 2], u3 = stageR[i + 3];
    int s0 = stageS[i], s1 = stageS[i + 1], s2 = stageS[i + 2], s3 = stageS[i + 3];
    while (true) {
      float g0 = h1f(xl[s0 * 64]);
      float g1 = h1f(xl[s1 * 64]);
      float g2 = h1f(xl[s2 * 64]);
      float g3 = h1f(xl[s3 * 64]);
      i += 4;
      bool more = (hi - i) >= 4;
      int ip = more ? i : lo;
      uint4 v0 = stageR[ip], v1 = stageR[ip + 1], v2 = stageR[ip + 2], v3 = stageR[ip + 3];
      int t0 = stageS[ip], t1 = stageS[ip + 1], t2 = stageS[ip + 2], t3 = stageS[ip + 3];
      float m0, m1, m2, m3;
      PROJH(m0, u0); PROJH(m1, u1); PROJH(m2, u2); PROJH(m3, u3);
      int d0 = (int)((u0.w >> 16) & 127u), d1 = (int)((u1.w >> 16) & 127u);
      int d2 = (int)((u2.w >> 16) & 127u), d3 = (int)((u3.w >> 16) & 127u);
      atomicAdd(&acc[d0][lane], fmaxf(m0 + g0, 0.f));
      atomicAdd(&acc[d1][lane], fmaxf(m1 + g1, 0.f));
      atomicAdd(&acc[d2][lane], fmaxf(m2 + g2, 0.f));
      atomicAdd(&acc[d3][lane], fmaxf(m3 + g3, 0.f));
      u0 = v0; u1 = v1; u2 = v2; u3 = v3;
      s0 = t0; s1 = t1; s2 = t2; s3 = t3;
      if (!more) break;
    }
  }
  for (; i < hi; i++) {
    uint4 u = stageR[i];
    int sn = stageS[i];
    float m;
    PROJH(m, u);
    int d = (int)((u.w >> 16) & 127u);
    atomicAdd(&acc[d][lane], fmaxf(m + h1f(xl[sn * 64]), 0.f));
  }
  __syncthreads();
  // per-node: h = ep*x + acc; t = h@w1 + b1; stats
  int n0 = blockIdx.x << 7;
  float s = 0.f, ss = 0.f;
  for (int j = wv; j < 128; j += 4) {
    int n = n0 + j;
    if (n >= NN) break;
    float h = ep * xin[n * 64 + lane] + acc[j][lane];
    hb[wv][lane] = h;  // same-wave LDS exchange (in-order DS pipe)
    float t = b1c;
#pragma unroll
    for (int k = 0; k < 64; k++) t = fmaf(hb[wv][k], wl[k * 64 + lane], t);
    tbuf[n * 64 + lane] = t;
    s += t;
    ss += t * t;
  }
  double* dsum = (double*)stats;
  red[tid] = s;
  __syncthreads();
  if (tid < 64) unsafeAtomicAdd(&dsum[tid], (double)(red[tid] + red[tid + 64] + red[tid + 128] + red[tid + 192]));
  __syncthreads();
  red[tid] = ss;
  __syncthreads();
  if (tid < 64) unsafeAtomicAdd(&dsum[64 + tid], (double)(red[tid] + red[tid + 64] + red[tid + 128] + red[tid + 192]));
}

// ===================== slim-tier kernels (fallback) ==========================
__global__ __launch_bounds__(256) void count_kernel(const int* __restrict__ dst,
                                                    int* __restrict__ cnt) {
  int stride = gridDim.x * 256;
  for (int e = blockIdx.x * 256 + threadIdx.x; e < NE; e += stride)
    atomicAdd(&cnt[dst[e]], 1);
}

__global__ __launch_bounds__(1024) void scan_kernel(const int* __restrict__ cnt,
                                                    int* __restrict__ rowptr,
                                                    int* __restrict__ ofs) {
  __shared__ int bsum[1024];
  int tid = threadIdx.x;
  const int CHS = (NN + 1023) / 1024;
  int lo = tid * CHS, hi = lo + CHS < NN ? lo + CHS : NN;
  if (lo > NN) lo = NN;
  if (hi < lo) hi = lo;
  int s = 0;
  for (int i = lo; i < hi; i++) s += cnt[i];
  bsum[tid] = s;
  __syncthreads();
  for (int off = 1; off < 1024; off <<= 1) {
    int v = bsum[tid];
    int u = (tid >= off) ? bsum[tid - off] : 0;
    __syncthreads();
    bsum[tid] = v + u;
    __syncthreads();
  }
  int pre = (tid == 0) ? 0 : bsum[tid - 1];
  for (int i = lo; i < hi; i++) {
    int cv = cnt[i];
    rowptr[i] = pre;
    ofs[i] = pre;
    pre += cv;
  }
  if (tid == 1023) rowptr[NN] = pre;
}

__global__ __launch_bounds__(256) void scatter1_kernel(
    const int* __restrict__ dst, int* __restrict__ ofs, int* __restrict__ eid_s) {
  int stride = gridDim.x * 256;
  for (int e = blockIdx.x * 256 + threadIdx.x; e < NE; e += stride) {
    int pos = atomicAdd(&ofs[dst[e]], 1);
    eid_s[pos] = e;
  }
}

__global__ __launch_bounds__(256) void l1agg_kernel(
    const int* __restrict__ rowptr, const int* __restrict__ eid_s,
    const int* __restrict__ src, const float* __restrict__ ea,
    const float* __restrict__ x, const float* __restrict__ elw,
    const float* __restrict__ elb, float* __restrict__ agg) {
  float w0[7], w1r[7];
#pragma unroll
  for (int k = 0; k < 7; k++) { w0[k] = elw[k * 2]; w1r[k] = elw[k * 2 + 1]; }
  float b0 = elb[0], b1 = elb[1];
  int stride = gridDim.x * 256;
  for (int n = blockIdx.x * 256 + threadIdx.x; n < NN; n += stride) {
    int r0 = rowptr[n], r1 = rowptr[n + 1];
    float a0 = 0.f, a1 = 0.f;
    for (int i = r0; i < r1; i++) {
      int e = eid_s[i];
      int sn = src[e];
      float m0 = b0, m1 = b1;
#pragma unroll
      for (int k = 0; k < 7; k++) {
        float a = ea[e * 7 + k];
        m0 = fmaf(a, w0[k], m0);
        m1 = fmaf(a, w1r[k], m1);
      }
      m0 = fmaxf(m0 + x[sn * 2 + 0], 0.f);
      m1 = fmaxf(m1 + x[sn * 2 + 1], 0.f);
      a0 += m0; a1 += m1;
    }
    agg[n * 2 + 0] = a0;
    agg[n * 2 + 1] = a1;
  }
}

__global__ __launch_bounds__(256) void gine64s_kernel(
    const int* __restrict__ rowptr, const int* __restrict__ eid_s,
    const int* __restrict__ src, const float* __restrict__ ea,
    const float* __restrict__ xin, const float* __restrict__ elw,
    const float* __restrict__ elb, const float* __restrict__ w1,
    const float* __restrict__ b1, const float* __restrict__ eps_p,
    float* __restrict__ tbuf, float* __restrict__ stats) {
  __shared__ float wl[64 * 64];
  __shared__ float hb[4][64];
  __shared__ float red[256];
  int tid = threadIdx.x, lane = tid & 63, wv = tid >> 6;
  for (int i = tid; i < 64 * 64; i += 256) wl[i] = w1[i];
  float wel[7];
#pragma unroll
  for (int k = 0; k < 7; k++) wel[k] = elw[k * 64 + lane];
  float bel = elb[lane], b1c = b1[lane];
  float ep = 1.0f + *eps_p;
  float s = 0.f, ss = 0.f;
  __syncthreads();
  int nw = gridDim.x * 4;
  for (int n = blockIdx.x * 4 + wv; n < NN; n += nw) {
    int r0 = rowptr[n], r1 = rowptr[n + 1];
    float acc = 0.f;
    for (int i = r0; i < r1; i++) {
      int e = eid_s[i];
      int sn = src[e];
      float m = bel;
#pragma unroll
      for (int k = 0; k < 7; k++) m = fmaf(ea[e * 7 + k], wel[k], m);
      m += xin[sn * 64 + lane];
      acc += fmaxf(m, 0.f);
    }
    float h = ep * xin[n * 64 + lane] + acc;
    hb[wv][lane] = h;
    float t = b1c;
#pragma unroll
    for (int k = 0; k < 64; k++) t = fmaf(hb[wv][k], wl[k * 64 + lane], t);
    tbuf[n * 64 + lane] = t;
    s += t;
    ss += t * t;
  }
  double* dsum = (double*)stats;
  red[tid] = s;
  __syncthreads();
  if (tid < 64) unsafeAtomicAdd(&dsum[tid], (double)(red[tid] + red[tid + 64] + red[tid + 128] + red[tid + 192]));
  __syncthreads();
  red[tid] = ss;
  __syncthreads();
  if (tid < 64) unsafeAtomicAdd(&dsum[64 + tid], (double)(red[tid] + red[tid + 64] + red[tid + 128] + red[tid + 192]));
}

// ===================== legacy (fallback tier B) kernels ======================
__global__ __launch_bounds__(256) void edge1_kernel(
    const float* __restrict__ x, const float* __restrict__ ea,
    const int* __restrict__ src, const int* __restrict__ dst,
    const float* __restrict__ elw, const float* __restrict__ elb,
    float* __restrict__ agg) {
  float w0[7], w1[7];
#pragma unroll
  for (int k = 0; k < 7; k++) { w0[k] = elw[k * 2]; w1[k] = elw[k * 2 + 1]; }
  float b0 = elb[0], b1 = elb[1];
  int stride = gridDim.x * 256;
  for (int e = blockIdx.x * 256 + threadIdx.x; e < NE; e += stride) {
    int s = src[e], d = dst[e];
    float m0 = b0, m1 = b1;
#pragma unroll
    for (int k = 0; k < 7; k++) {
      float a = ea[e * 7 + k];
      m0 = fmaf(a, w0[k], m0);
      m1 = fmaf(a, w1[k], m1);
    }
    m0 = fmaxf(m0 + x[s * 2 + 0], 0.f);
    m1 = fmaxf(m1 + x[s * 2 + 1], 0.f);
    unsafeAtomicAdd(&agg[d * 2 + 0], m0);
    unsafeAtomicAdd(&agg[d * 2 + 1], m1);
  }
}

__global__ __launch_bounds__(256) void edge64_kernel(
    const float* __restrict__ xin, const float* __restrict__ ea,
    const int* __restrict__ src, const int* __restrict__ dst,
    const float* __restrict__ elw, const float* __restrict__ elb,
    float* __restrict__ agg) {
  int lane = threadIdx.x & 63;
  int wid = (blockIdx.x * 256 + threadIdx.x) >> 6;
  int nw = (gridDim.x * 256) >> 6;
  float w[7];
#pragma unroll
  for (int k = 0; k < 7; k++) w[k] = elw[k * 64 + lane];
  float b = elb[lane];
  for (int e = wid; e < NE; e += nw) {
    int eu = __builtin_amdgcn_readfirstlane(e);
    int s = src[eu];
    int d = dst[eu];
    float m = b;
#pragma unroll
    for (int k = 0; k < 7; k++) m = fmaf(ea[eu * 7 + k], w[k], m);
    m += xin[s * 64 + lane];
    m = fmaxf(m, 0.f);
    unsafeAtomicAdd(&agg[d * 64 + lane], m);
  }
}

__global__ __launch_bounds__(256) void nodeA64_kernel(
    const float* __restrict__ xin, float* __restrict__ tbuf,
    const float* __restrict__ w1, const float* __restrict__ b1,
    const float* __restrict__ eps_p, float* __restrict__ stats) {
  __shared__ float wl[64 * 64];
  __shared__ float hbuf[4][64];
  __shared__ float red[256];
  int tid = threadIdx.x;
  int c = tid & 63, nl = tid >> 6;
  for (int i = tid; i < 64 * 64; i += 256) wl[i] = w1[i];
  float ep = 1.0f + *eps_p;
  float bc = b1[c];
  float s = 0.f, ss = 0.f;
  __syncthreads();
  for (int n0 = blockIdx.x * 4; n0 < NN; n0 += gridDim.x * 4) {
    int n = n0 + nl;
    bool valid = n < NN;
    float h = 0.f;
    if (valid) h = ep * xin[n * 64 + c] + tbuf[n * 64 + c];
    hbuf[nl][c] = h;
    __syncthreads();
    if (valid) {
      float t = bc;
#pragma unroll
      for (int k = 0; k < 64; k++) t = fmaf(hbuf[nl][k], wl[k * 64 + c], t);
      tbuf[n * 64 + c] = t;
      s += t;
      ss += t * t;
    }
    __syncthreads();
  }
  double* dsum = (double*)stats;
  red[tid] = s;
  __syncthreads();
  if (tid < 64) unsafeAtomicAdd(&dsum[tid], (double)(red[tid] + red[tid + 64] + red[tid + 128] + red[tid + 192]));
  __syncthreads();
  red[tid] = ss;
  __syncthreads();
  if (tid < 64) unsafeAtomicAdd(&dsum[64 + tid], (double)(red[tid] + red[tid + 64] + red[tid + 128] + red[tid + 192]));
}

// ===================== shared node kernels ===================================
__global__ __launch_bounds__(256) void nodeA2_kernel(
    const float* __restrict__ x, const float* __restrict__ agg1,
    float* __restrict__ tbuf, const float* __restrict__ w1,
    const float* __restrict__ b1, const float* __restrict__ eps_p,
    float* __restrict__ stats) {
  __shared__ float red[256];
  int tid = threadIdx.x;
  int c = tid & 63, nl = tid >> 6;
  float wa = w1[c], wb = w1[64 + c], bc = b1[c];
  float ep = 1.0f + *eps_p;
  float s = 0.f, ss = 0.f;
  for (int n0 = blockIdx.x * 4; n0 < NN; n0 += gridDim.x * 4) {
    int n = n0 + nl;
    if (n < NN) {
      float h0 = ep * x[n * 2 + 0] + agg1[n * 2 + 0];
      float h1 = ep * x[n * 2 + 1] + agg1[n * 2 + 1];
      float t = fmaf(h1, wb, fmaf(h0, wa, bc));
      tbuf[n * 64 + c] = t;
      s += t;
      ss += t * t;
    }
  }
  double* dsum = (double*)stats;
  red[tid] = s;
  __syncthreads();
  if (tid < 64) unsafeAtomicAdd(&dsum[tid], (double)(red[tid] + red[tid + 64] + red[tid + 128] + red[tid + 192]));
  __syncthreads();
  red[tid] = ss;
  __syncthreads();
  if (tid < 64) unsafeAtomicAdd(&dsum[64 + tid], (double)(red[tid] + red[tid + 64] + red[tid + 128] + red[tid + 192]));
}

__global__ __launch_bounds__(256) void nodeB_kernel(
    const float* __restrict__ tin, float* __restrict__ outb,
    const float* __restrict__ w2, const float* __restrict__ b2,
    const float* __restrict__ stats, const float* __restrict__ g,
    const float* __restrict__ bt, unsigned short* __restrict__ xh) {
  __shared__ float wl[64 * 64];
  __shared__ float ubuf[4][64];
  __shared__ float scsh[128];
  int tid = threadIdx.x;
  int c = tid & 63, nl = tid >> 6;
  for (int i = tid; i < 64 * 64; i += 256) wl[i] = w2[i];
  if (tid < 64) {
    const double* ds = (const double*)stats;
    double m = ds[tid] / (double)NN;
    double v = ds[64 + tid] / (double)NN - m * m;
    float sc = g[tid] * (float)(1.0 / sqrt(v + 1e-5));
    scsh[tid] = sc;
    scsh[64 + tid] = bt[tid] - (float)m * sc;
  }
  float bc = b2[c];
  __syncthreads();
  float scale = scsh[c], shift = scsh[64 + c];
  for (int n0 = blockIdx.x * 4; n0 < NN; n0 += gridDim.x * 4) {
    int n = n0 + nl;
    bool valid = n < NN;
    float u = 0.f;
    if (valid) {
      float t = tin[n * 64 + c];
      u = fmaxf(fmaf(t, scale, shift), 0.f);
    }
    ubuf[nl][c] = u;
    __syncthreads();
    if (valid) {
      float o = bc;
#pragma unroll
      for (int k = 0; k < 64; k++) o = fmaf(ubuf[nl][k], wl[k * 64 + c], o);
      o = fmaxf(o, 0.f);
      outb[n * 64 + c] = o;
      if (xh) xh[n * 64 + c] = f1h(o);
    }
    __syncthreads();
  }
}

__global__ __launch_bounds__(256) void final_kernel(
    const float* __restrict__ xin, const float* __restrict__ regw,
    const float* __restrict__ regb, const float* __restrict__ endw,
    const float* __restrict__ endb, float* __restrict__ out) {
  __shared__ float wl[64 * 128];
  __shared__ float eb[256];
  int tid = threadIdx.x;
  int node = blockIdx.x * 256 + tid;
  bool valid = node < NN;
  float xr[64];
  if (valid) {
    const float4* xp = (const float4*)(xin + node * 64);
#pragma unroll
    for (int k4 = 0; k4 < 16; k4++) {
      float4 v = xp[k4];
      xr[k4 * 4 + 0] = v.x; xr[k4 * 4 + 1] = v.y;
      xr[k4 * 4 + 2] = v.z; xr[k4 * 4 + 3] = v.w;
    }
  }
  float y = 0.f;
  for (int ch = 0; ch < 4; ch++) {
    int j0 = ch * 125;
    __syncthreads();
    for (int idx = tid; idx < 64 * 125; idx += 256) {
      int k = idx / 125;
      int jl = idx - k * 125;
      wl[k * 128 + jl] = regw[k * 500 + j0 + jl];
    }
    if (tid < 125) { eb[tid] = regb[j0 + tid]; eb[128 + tid] = endw[j0 + tid]; }
    __syncthreads();
    if (valid) {
      int jl = 0;
      for (; jl + 4 <= 125; jl += 4) {
        float t0 = eb[jl], t1 = eb[jl + 1], t2 = eb[jl + 2], t3 = eb[jl + 3];
#pragma unroll
        for (int k = 0; k < 64; k++) {
          float4 w4 = *(const float4*)&wl[k * 128 + jl];
          float xv = xr[k];
          t0 = fmaf(xv, w4.x, t0);
          t1 = fmaf(xv, w4.y, t1);
          t2 = fmaf(xv, w4.z, t2);
          t3 = fmaf(xv, w4.w, t3);
        }
        t0 = t0 >= 0.f ? t0 : 0.01f * t0;
        t1 = t1 >= 0.f ? t1 : 0.01f * t1;
        t2 = t2 >= 0.f ? t2 : 0.01f * t2;
        t3 = t3 >= 0.f ? t3 : 0.01f * t3;
        y += t0 * eb[128 + jl] + t1 * eb[128 + jl + 1] + t2 * eb[128 + jl + 2] + t3 * eb[128 + jl + 3];
      }
      {
        float t = eb[124];
#pragma unroll
        for (int k = 0; k < 64; k++) t = fmaf(xr[k], wl[k * 128 + 124], t);
        t = t >= 0.f ? t : 0.01f * t;
        y += t * eb[128 + 124];
      }
    }
  }
  if (valid) out[node] = y + endb[0];
}

extern "C" void kernel_launch(void* const* d_in, const int* in_sizes, int n_in,
                              void* d_out, int out_size, void* d_ws, size_t ws_size,
                              hipStream_t stream) {
  const float* x    = (const float*)d_in[0];
  const float* ea   = (const float*)d_in[1];
  const int*   ei   = (const int*)d_in[2];
  const float* eps1 = (const float*)d_in[4];
  const float* el1w = (const float*)d_in[5];
  const float* el1b = (const float*)d_in[6];
  const float* n1w1 = (const float*)d_in[7];
  const float* n1b1 = (const float*)d_in[8];
  const float* n1g  = (const float*)d_in[9];
  const float* n1bt = (const float*)d_in[10];
  const float* n1w2 = (const float*)d_in[11];
  const float* n1b2 = (const float*)d_in[12];
  const float* eps2 = (const float*)d_in[13];
  const float* el2w = (const float*)d_in[14];
  const float* el2b = (const float*)d_in[15];
  const float* n2w1 = (const float*)d_in[16];
  const float* n2b1 = (const float*)d_in[17];
  const float* n2g  = (const float*)d_in[18];
  const float* n2bt = (const float*)d_in[19];
  const float* n2w2 = (const float*)d_in[20];
  const float* n2b2 = (const float*)d_in[21];
  const float* regw = (const float*)d_in[22];
  const float* regb = (const float*)d_in[23];
  const float* endw = (const float*)d_in[24];
  const float* endb = (const float*)d_in[25];
  const int* srcp = ei;
  const int* dstp = ei + NE;

  // ---- tier-A layout (float offsets) ----
  const size_t o_stats    = 0;         // 768 = 3 layers × 128 doubles [memset]
  const size_t o_binstart = 768;       // NBIN+1 ints (pad 784)
  const size_t o_share    = 1552;      // 200192: blkhist[256*782] -> later agg1
  const size_t o_buf0     = 201744;    // N*64
  const size_t o_buf1     = 6601744;   // N*64
  const size_t o_xh       = 13001744;  // N*64 fp16 (slim: eid E ints)
  const size_t o_aggslim  = 16201744;  // N*2 (slim tier only)
  const size_t o_stageR   = 16201744;  // E uint4 (tier A)
  const size_t o_stageS   = 29001744;  // E ints  (tier A)
  const size_t needA2 = (o_stageS + (size_t)NE) * 4;       // ~128.8 MB
  const size_t needA1 = (o_aggslim + (size_t)NN * 2) * 4;  // ~65.6 MB
  const size_t needB  = (2 * 6600000 + 384) * 4;           // ~52.8 MB

  float* wsf = (float*)d_ws;

  if (ws_size >= needA2) {
    // =================== tier A: binned, scatter-free ===================
    float* stats0 = wsf + o_stats;
    float* stats1 = wsf + o_stats + 256;
    float* stats2 = wsf + o_stats + 512;
    int* binstart = (int*)(wsf + o_binstart);
    int* blkhist  = (int*)(wsf + o_share);
    float* agg1   = wsf + o_share;  // reuses blkhist region (dead after scatk)
    float* buf0   = wsf + o_buf0;
    float* buf1   = wsf + o_buf1;
    unsigned short* xh = (unsigned short*)(wsf + o_xh);
    uint4* stageR = (uint4*)(wsf + o_stageR);
    int* stageS   = (int*)(wsf + o_stageS);

    hipMemsetAsync(wsf, 0, 768 * sizeof(float), stream);  // stats only

    // ---- bin partition (once, shared by all 3 layers) ----
    histk_kernel<<<NBLK, 256, 0, stream>>>(dstp, blkhist);
    scank_kernel<<<1, 1024, 0, stream>>>(blkhist, binstart);
    scatk_kernel<<<NBLK, 256, 0, stream>>>(srcp, dstp, ea, blkhist,
                                           stageR, stageS);

    // ---- layer 1 ----
    gine2b_kernel<<<NBIN, 256, 0, stream>>>(binstart, stageR, stageS, x,
                                            el1w, el1b, agg1);
    nodeA2_kernel<<<2048, 256, 0, stream>>>(x, agg1, buf1, n1w1, n1b1, eps1, stats0);
    nodeB_kernel<<<2048, 256, 0, stream>>>(buf1, buf1, n1w2, n1b2, stats0,
                                           n1g, n1bt, xh);

    // ---- layers 2,3 (shared weights) ----
    gine64b_kernel<<<NBIN, 256, 0, stream>>>(binstart, stageR, stageS, buf1, xh,
                                             el2w, el2b, n2w1, n2b1, eps2,
                                             buf0, stats1);
    nodeB_kernel<<<2048, 256, 0, stream>>>(buf0, buf0, n2w2, n2b2, stats1,
                                           n2g, n2bt, xh);
    gine64b_kernel<<<NBIN, 256, 0, stream>>>(binstart, stageR, stageS, buf0, xh,
                                             el2w, el2b, n2w1, n2b1, eps2,
                                             buf1, stats2);
    nodeB_kernel<<<2048, 256, 0, stream>>>(buf1, buf1, n2w2, n2b2, stats2,
                                           n2g, n2bt, nullptr);
    final_kernel<<<(NN + 255) / 256, 256, 0, stream>>>(buf1, regw, regb, endw,
                                                       endb, (float*)d_out);
    return;
  }

  if (ws_size >= needA1) {
    // =================== slim tier: eid CSR ===================
    float* stats0 = wsf + o_stats;
    float* stats1 = wsf + o_stats + 256;
    float* stats2 = wsf + o_stats + 512;
    int* cnt    = (int*)(wsf + o_share);           // NN ints
    int* rowptr = (int*)(wsf + o_share) + NN;      // NN+1 ints (fits 200192)
    float* buf0 = wsf + o_buf0;
    float* buf1 = wsf + o_buf1;
    int* eid    = (int*)(wsf + o_xh);              // E ints
    float* agg1 = wsf + o_aggslim;

    hipMemsetAsync(wsf, 0, 768 * sizeof(float), stream);
    hipMemsetAsync(cnt, 0, NN * sizeof(int), stream);
    count_kernel<<<4096, 256, 0, stream>>>(dstp, cnt);
    scan_kernel<<<1, 1024, 0, stream>>>(cnt, rowptr, cnt);
    scatter1_kernel<<<4096, 256, 0, stream>>>(dstp, cnt, eid);
    l1agg_kernel<<<391, 256, 0, stream>>>(rowptr, eid, srcp, ea, x, el1w, el1b,
                                          agg1);
    nodeA2_kernel<<<2048, 256, 0, stream>>>(x, agg1, buf1, n1w1, n1b1, eps1, stats0);
    nodeB_kernel<<<2048, 256, 0, stream>>>(buf1, buf1, n1w2, n1b2, stats0,
                                           n1g, n1bt, nullptr);
    float* cur = buf1;
    float* wrk = buf0;
    float* sl[2] = {stats1, stats2};
    for (int l = 0; l < 2; l++) {
      gine64s_kernel<<<4096, 256, 0, stream>>>(rowptr, eid, srcp, ea, cur,
                                               el2w, el2b, n2w1, n2b1, eps2,
                                               wrk, sl[l]);
      nodeB_kernel<<<2048, 256, 0, stream>>>(wrk, wrk, n2w2, n2b2, sl[l],
                                             n2g, n2bt, nullptr);
      float* tmp = cur; cur = wrk; wrk = tmp;
    }
    final_kernel<<<(NN + 255) / 256, 256, 0, stream>>>(cur, regw, regb, endw,
                                                       endb, (float*)d_out);
    return;
  }

  // ================= fallback tier B (round-1 proven path) =================
  if (ws_size < needB) return;
  const size_t BUF = 6600000;
  float* buf0 = (float*)d_ws;
  float* buf1 = buf0 + BUF;
  float* stats = buf1 + BUF;

  float* t1 = buf1;
  float* agg1 = buf1 + NN * 64;
  hipMemsetAsync(agg1, 0, NN * 2 * sizeof(float), stream);
  hipMemsetAsync(stats, 0, 128 * sizeof(double), stream);
  edge1_kernel<<<2048, 256, 0, stream>>>(x, ea, srcp, dstp, el1w, el1b, agg1);
  nodeA2_kernel<<<2048, 256, 0, stream>>>(x, agg1, t1, n1w1, n1b1, eps1, stats);
  nodeB_kernel<<<2048, 256, 0, stream>>>(t1, buf1, n1w2, n1b2, stats, n1g, n1bt,
                                         nullptr);

  float* cur = buf1;
  float* wrk = buf0;
  for (int l = 0; l < 2; l++) {
    hipMemsetAsync(wrk, 0, NN * 64 * sizeof(float), stream);
    hipMemsetAsync(stats, 0, 128 * sizeof(double), stream);
    edge64_kernel<<<2048, 256, 0, stream>>>(cur, ea, srcp, dstp, el2w, el2b, wrk);
    nodeA64_kernel<<<2048, 256, 0, stream>>>(cur, wrk, n2w1, n2b1, eps2, stats);
    nodeB_kernel<<<2048, 256, 0, stream>>>(wrk, wrk, n2w2, n2b2, stats, n2g, n2bt,
                                           nullptr);
    float* tmp = cur; cur = wrk; wrk = tmp;
  }

  final_kernel<<<(NN + 255) / 256, 256, 0, stream>>>(cur, regw, regb, endw, endb,
                                                     (float*)d_out);
}

// Round 12
// 1344.138 us; speedup vs baseline: 2.4445x; 2.4445x over previous
//
#include <hip/hip_runtime.h>
#include <hip/hip_fp16.h>

#define NN 100000
#define NE 3200000

// ---------- fp16 pack/unpack helpers ----------
__device__ inline unsigned pkh(float a, float b) {
  __half2 h;
  h.x = __float2half(a);
  h.y = __float2half(b);
  unsigned u;
  __builtin_memcpy(&u, &h, 4);
  return u;
}
__device__ inline float2 uph(unsigned u) {
  __half2 h;
  __builtin_memcpy(&h, &u, 4);
  return __half22float2(h);
}
__device__ inline float h1f(unsigned short v) {
  __half h;
  __builtin_memcpy(&h, &v, 2);
  return __half2float(h);
}
__device__ inline unsigned short f1h(float f) {
  __half h = __float2half(f);
  unsigned short u;
  __builtin_memcpy(&u, &h, 2);
  return u;
}

// ===================== CSR build =====================
__global__ __launch_bounds__(256) void count_kernel(const int* __restrict__ dst,
                                                    int* __restrict__ cnt) {
  int stride = gridDim.x * 256;
  for (int e = blockIdx.x * 256 + threadIdx.x; e < NE; e += stride)
    atomicAdd(&cnt[dst[e]], 1);
}

// single-block exclusive scan over NN counts -> rowptr[0..NN]; ofs=running copy
__global__ __launch_bounds__(1024) void scan_kernel(const int* __restrict__ cnt,
                                                    int* __restrict__ rowptr,
                                                    int* __restrict__ ofs) {
  __shared__ int bsum[1024];
  int tid = threadIdx.x;
  const int CH = (NN + 1023) / 1024;
  int lo = tid * CH, hi = lo + CH < NN ? lo + CH : NN;
  if (lo > NN) lo = NN;
  if (hi < lo) hi = lo;
  int s = 0;
  for (int i = lo; i < hi; i++) s += cnt[i];
  bsum[tid] = s;
  __syncthreads();
  for (int off = 1; off < 1024; off <<= 1) {
    int v = bsum[tid];
    int u = (tid >= off) ? bsum[tid - off] : 0;
    __syncthreads();
    bsum[tid] = v + u;
    __syncthreads();
  }
  int pre = (tid == 0) ? 0 : bsum[tid - 1];
  for (int i = lo; i < hi; i++) {
    int cv = cnt[i];
    rowptr[i] = pre;
    ofs[i] = pre;
    pre += cv;
  }
  if (tid == 1023) rowptr[NN] = pre;
}

// packed fp16 scatter + fused layer-1 message:
//   erec[pos] = uint4 of 7×fp16 ea (+pad)   (16B record)
//   esrc[pos] = src                          (4B)
//   msg1[pos] = relu(x[src,:2] + ea@el1w + el1b) as float2
__global__ __launch_bounds__(256) void scatter2h_kernel(
    const int* __restrict__ src, const int* __restrict__ dst,
    const float* __restrict__ ea, int* __restrict__ ofs,
    uint4* __restrict__ erec, int* __restrict__ esrc,
    const float* __restrict__ x, const float* __restrict__ elw,
    const float* __restrict__ elb, float* __restrict__ msg1) {
  float w0[7], w1r[7];
#pragma unroll
  for (int k = 0; k < 7; k++) { w0[k] = elw[k * 2]; w1r[k] = elw[k * 2 + 1]; }
  float b0 = elb[0], b1 = elb[1];
  int stride = gridDim.x * 256;
  for (int e = blockIdx.x * 256 + threadIdx.x; e < NE; e += stride) {
    int sn = src[e];
    int pos = atomicAdd(&ofs[dst[e]], 1);
    float av[7];
#pragma unroll
    for (int k = 0; k < 7; k++) av[k] = ea[e * 7 + k];
    uint4 r;
    r.x = pkh(av[0], av[1]);
    r.y = pkh(av[2], av[3]);
    r.z = pkh(av[4], av[5]);
    r.w = pkh(av[6], 0.f);
    erec[pos] = r;
    esrc[pos] = sn;
    float m0 = b0, m1 = b1;
#pragma unroll
    for (int k = 0; k < 7; k++) {
      m0 = fmaf(av[k], w0[k], m0);
      m1 = fmaf(av[k], w1r[k], m1);
    }
    m0 = fmaxf(m0 + x[sn * 2 + 0], 0.f);
    m1 = fmaxf(m1 + x[sn * 2 + 1], 0.f);
    float2 mv; mv.x = m0; mv.y = m1;
    ((float2*)msg1)[pos] = mv;
  }
}

// slim scatter: sorted edge ids only
__global__ __launch_bounds__(256) void scatter1_kernel(
    const int* __restrict__ dst, int* __restrict__ ofs, int* __restrict__ eid_s) {
  int stride = gridDim.x * 256;
  for (int e = blockIdx.x * 256 + threadIdx.x; e < NE; e += stride) {
    int pos = atomicAdd(&ofs[dst[e]], 1);
    eid_s[pos] = e;
  }
}

// ============ layer 1 (packed tier): segment-sum of precomputed msg1 =========
__global__ __launch_bounds__(256) void l1sum_kernel(
    const int* __restrict__ rowptr, const float* __restrict__ msg1,
    float* __restrict__ agg) {
  int stride = gridDim.x * 256;
  for (int n = blockIdx.x * 256 + threadIdx.x; n < NN; n += stride) {
    int r0 = rowptr[n], r1 = rowptr[n + 1];
    float a0 = 0.f, a1 = 0.f;
    const float2* mp = (const float2*)msg1;
    for (int i = r0; i < r1; i++) {
      float2 v = mp[i];
      a0 += v.x;
      a1 += v.y;
    }
    agg[n * 2 + 0] = a0;
    agg[n * 2 + 1] = a1;
  }
}

// =========== layer 1 slim-tier aggregate (thread per node, eid CSR) ==========
__global__ __launch_bounds__(256) void l1agg_kernel(
    const int* __restrict__ rowptr, const int* __restrict__ eid_s,
    const int* __restrict__ src, const float* __restrict__ ea,
    const float* __restrict__ x, const float* __restrict__ elw,
    const float* __restrict__ elb, float* __restrict__ agg) {
  float w0[7], w1r[7];
#pragma unroll
  for (int k = 0; k < 7; k++) { w0[k] = elw[k * 2]; w1r[k] = elw[k * 2 + 1]; }
  float b0 = elb[0], b1 = elb[1];
  int stride = gridDim.x * 256;
  for (int n = blockIdx.x * 256 + threadIdx.x; n < NN; n += stride) {
    int r0 = rowptr[n], r1 = rowptr[n + 1];
    float a0 = 0.f, a1 = 0.f;
    for (int i = r0; i < r1; i++) {
      int e = eid_s[i];
      int sn = src[e];
      float m0 = b0, m1 = b1;
#pragma unroll
      for (int k = 0; k < 7; k++) {
        float a = ea[e * 7 + k];
        m0 = fmaf(a, w0[k], m0);
        m1 = fmaf(a, w1r[k], m1);
      }
      m0 = fmaxf(m0 + x[sn * 2 + 0], 0.f);
      m1 = fmaxf(m1 + x[sn * 2 + 1], 0.f);
      a0 += m0; a1 += m1;
    }
    agg[n * 2 + 0] = a0;
    agg[n * 2 + 1] = a1;
  }
}

#define PROJH(m, u) do { \
  float2 q0 = uph((u).x), q1 = uph((u).y), q2 = uph((u).z), q3 = uph((u).w); \
  m = bel; \
  m = fmaf(q0.x, wel[0], m); m = fmaf(q0.y, wel[1], m); \
  m = fmaf(q1.x, wel[2], m); m = fmaf(q1.y, wel[3], m); \
  m = fmaf(q2.x, wel[4], m); m = fmaf(q2.y, wel[5], m); \
  m = fmaf(q3.x, wel[6], m); } while (0)

// ====== layers 2/3 fused, fp16 records + fp16 gathers, 4-deep pipeline =======
__global__ __launch_bounds__(256) void gine64h_kernel(
    const int* __restrict__ rowptr, const uint4* __restrict__ erec,
    const int* __restrict__ esrc, const float* __restrict__ xin,
    const unsigned short* __restrict__ xh, const float* __restrict__ elw,
    const float* __restrict__ elb, const float* __restrict__ w1,
    const float* __restrict__ b1, const float* __restrict__ eps_p,
    float* __restrict__ tbuf, float* __restrict__ stats) {
  __shared__ float wl[64 * 64];
  __shared__ float hb[4][64];
  __shared__ float red[256];
  int tid = threadIdx.x, lane = tid & 63, wv = tid >> 6;
  for (int i2 = tid; i2 < 64 * 64; i2 += 256) wl[i2] = w1[i2];
  float wel[7];
#pragma unroll
  for (int k = 0; k < 7; k++) wel[k] = elw[k * 64 + lane];
  float bel = elb[lane], b1c = b1[lane];
  float ep = 1.0f + *eps_p;
  float s = 0.f, ss = 0.f;
  __syncthreads();
  const unsigned short* xl = xh + lane;
  int nw = gridDim.x * 4;
  for (int n = blockIdx.x * 4 + wv; n < NN; n += nw) {
    int r0 = rowptr[n], r1 = rowptr[n + 1];
    float acc = 0.f;
    int i = r0;
    int rem = r1 - r0;
    if (rem >= 4) {
      uint4 u0 = erec[i], u1 = erec[i + 1], u2 = erec[i + 2], u3 = erec[i + 3];
      int s0 = esrc[i], s1 = esrc[i + 1], s2 = esrc[i + 2], s3 = esrc[i + 3];
      while (true) {
        // issue 4 independent fp16 gathers (one cache line each)
        float g0 = h1f(xl[s0 * 64]);
        float g1 = h1f(xl[s1 * 64]);
        float g2 = h1f(xl[s2 * 64]);
        float g3 = h1f(xl[s3 * 64]);
        i += 4; rem -= 4;
        bool more = rem >= 4;
        int ip = more ? i : r0;  // dummy (valid) address when finishing
        // prefetch next group's records/srcs while gathers are in flight
        uint4 v0 = erec[ip], v1 = erec[ip + 1], v2 = erec[ip + 2], v3 = erec[ip + 3];
        int t0 = esrc[ip], t1 = esrc[ip + 1], t2 = esrc[ip + 2], t3 = esrc[ip + 3];
        // edge projections (independent of gathers)
        float m0, m1, m2, m3;
        PROJH(m0, u0); PROJH(m1, u1); PROJH(m2, u2); PROJH(m3, u3);
        acc += fmaxf(m0 + g0, 0.f);
        acc += fmaxf(m1 + g1, 0.f);
        acc += fmaxf(m2 + g2, 0.f);
        acc += fmaxf(m3 + g3, 0.f);
        u0 = v0; u1 = v1; u2 = v2; u3 = v3;
        s0 = t0; s1 = t1; s2 = t2; s3 = t3;
        if (!more) break;
      }
    }
    for (; i < r1; i++) {  // tail (0..3 edges)
      uint4 u = erec[i];
      int sn = esrc[i];
      float m;
      PROJH(m, u);
      m += h1f(xl[sn * 64]);
      acc += fmaxf(m, 0.f);
    }
    float h = ep * xin[n * 64 + lane] + acc;
    hb[wv][lane] = h;  // same-wave LDS exchange (in-order DS pipe)
    float t = b1c;
#pragma unroll
    for (int k = 0; k < 64; k++) t = fmaf(hb[wv][k], wl[k * 64 + lane], t);
    tbuf[n * 64 + lane] = t;
    s += t;
    ss += t * t;
  }
  double* dsum = (double*)stats;
  red[tid] = s;
  __syncthreads();
  if (tid < 64) unsafeAtomicAdd(&dsum[tid], (double)(red[tid] + red[tid + 64] + red[tid + 128] + red[tid + 192]));
  __syncthreads();
  red[tid] = ss;
  __syncthreads();
  if (tid < 64) unsafeAtomicAdd(&dsum[64 + tid], (double)(red[tid] + red[tid + 64] + red[tid + 128] + red[tid + 192]));
}

// ====== layers 2/3 slim-tier (eid CSR, unpipelined — fallback only) ==========
__global__ __launch_bounds__(256) void gine64s_kernel(
    const int* __restrict__ rowptr, const int* __restrict__ eid_s,
    const int* __restrict__ src, const float* __restrict__ ea,
    const float* __restrict__ xin, const float* __restrict__ elw,
    const float* __restrict__ elb, const float* __restrict__ w1,
    const float* __restrict__ b1, const float* __restrict__ eps_p,
    float* __restrict__ tbuf, float* __restrict__ stats) {
  __shared__ float wl[64 * 64];
  __shared__ float hb[4][64];
  __shared__ float red[256];
  int tid = threadIdx.x, lane = tid & 63, wv = tid >> 6;
  for (int i = tid; i < 64 * 64; i += 256) wl[i] = w1[i];
  float wel[7];
#pragma unroll
  for (int k = 0; k < 7; k++) wel[k] = elw[k * 64 + lane];
  float bel = elb[lane], b1c = b1[lane];
  float ep = 1.0f + *eps_p;
  float s = 0.f, ss = 0.f;
  __syncthreads();
  int nw = gridDim.x * 4;
  for (int n = blockIdx.x * 4 + wv; n < NN; n += nw) {
    int r0 = rowptr[n], r1 = rowptr[n + 1];
    float acc = 0.f;
    for (int i = r0; i < r1; i++) {
      int e = eid_s[i];
      int sn = src[e];
      float m = bel;
#pragma unroll
      for (int k = 0; k < 7; k++) m = fmaf(ea[e * 7 + k], wel[k], m);
      m += xin[sn * 64 + lane];
      acc += fmaxf(m, 0.f);
    }
    float h = ep * xin[n * 64 + lane] + acc;
    hb[wv][lane] = h;
    float t = b1c;
#pragma unroll
    for (int k = 0; k < 64; k++) t = fmaf(hb[wv][k], wl[k * 64 + lane], t);
    tbuf[n * 64 + lane] = t;
    s += t;
    ss += t * t;
  }
  double* dsum = (double*)stats;
  red[tid] = s;
  __syncthreads();
  if (tid < 64) unsafeAtomicAdd(&dsum[tid], (double)(red[tid] + red[tid + 64] + red[tid + 128] + red[tid + 192]));
  __syncthreads();
  red[tid] = ss;
  __syncthreads();
  if (tid < 64) unsafeAtomicAdd(&dsum[64 + tid], (double)(red[tid] + red[tid + 64] + red[tid + 128] + red[tid + 192]));
}

// ===================== legacy (fallback tier B) kernels ======================
__global__ __launch_bounds__(256) void edge1_kernel(
    const float* __restrict__ x, const float* __restrict__ ea,
    const int* __restrict__ src, const int* __restrict__ dst,
    const float* __restrict__ elw, const float* __restrict__ elb,
    float* __restrict__ agg) {
  float w0[7], w1[7];
#pragma unroll
  for (int k = 0; k < 7; k++) { w0[k] = elw[k * 2]; w1[k] = elw[k * 2 + 1]; }
  float b0 = elb[0], b1 = elb[1];
  int stride = gridDim.x * 256;
  for (int e = blockIdx.x * 256 + threadIdx.x; e < NE; e += stride) {
    int s = src[e], d = dst[e];
    float m0 = b0, m1 = b1;
#pragma unroll
    for (int k = 0; k < 7; k++) {
      float a = ea[e * 7 + k];
      m0 = fmaf(a, w0[k], m0);
      m1 = fmaf(a, w1[k], m1);
    }
    m0 = fmaxf(m0 + x[s * 2 + 0], 0.f);
    m1 = fmaxf(m1 + x[s * 2 + 1], 0.f);
    unsafeAtomicAdd(&agg[d * 2 + 0], m0);
    unsafeAtomicAdd(&agg[d * 2 + 1], m1);
  }
}

__global__ __launch_bounds__(256) void edge64_kernel(
    const float* __restrict__ xin, const float* __restrict__ ea,
    const int* __restrict__ src, const int* __restrict__ dst,
    const float* __restrict__ elw, const float* __restrict__ elb,
    float* __restrict__ agg) {
  int lane = threadIdx.x & 63;
  int wid = (blockIdx.x * 256 + threadIdx.x) >> 6;
  int nw = (gridDim.x * 256) >> 6;
  float w[7];
#pragma unroll
  for (int k = 0; k < 7; k++) w[k] = elw[k * 64 + lane];
  float b = elb[lane];
  for (int e = wid; e < NE; e += nw) {
    int eu = __builtin_amdgcn_readfirstlane(e);
    int s = src[eu];
    int d = dst[eu];
    float m = b;
#pragma unroll
    for (int k = 0; k < 7; k++) m = fmaf(ea[eu * 7 + k], w[k], m);
    m += xin[s * 64 + lane];
    m = fmaxf(m, 0.f);
    unsafeAtomicAdd(&agg[d * 64 + lane], m);
  }
}

__global__ __launch_bounds__(256) void nodeA64_kernel(
    const float* __restrict__ xin, float* __restrict__ tbuf,
    const float* __restrict__ w1, const float* __restrict__ b1,
    const float* __restrict__ eps_p, float* __restrict__ stats) {
  __shared__ float wl[64 * 64];
  __shared__ float hbuf[4][64];
  __shared__ float red[256];
  int tid = threadIdx.x;
  int c = tid & 63, nl = tid >> 6;
  for (int i = tid; i < 64 * 64; i += 256) wl[i] = w1[i];
  float ep = 1.0f + *eps_p;
  float bc = b1[c];
  float s = 0.f, ss = 0.f;
  __syncthreads();
  for (int n0 = blockIdx.x * 4; n0 < NN; n0 += gridDim.x * 4) {
    int n = n0 + nl;
    bool valid = n < NN;
    float h = 0.f;
    if (valid) h = ep * xin[n * 64 + c] + tbuf[n * 64 + c];
    hbuf[nl][c] = h;
    __syncthreads();
    if (valid) {
      float t = bc;
#pragma unroll
      for (int k = 0; k < 64; k++) t = fmaf(hbuf[nl][k], wl[k * 64 + c], t);
      tbuf[n * 64 + c] = t;
      s += t;
      ss += t * t;
    }
    __syncthreads();
  }
  double* dsum = (double*)stats;
  red[tid] = s;
  __syncthreads();
  if (tid < 64) unsafeAtomicAdd(&dsum[tid], (double)(red[tid] + red[tid + 64] + red[tid + 128] + red[tid + 192]));
  __syncthreads();
  red[tid] = ss;
  __syncthreads();
  if (tid < 64) unsafeAtomicAdd(&dsum[64 + tid], (double)(red[tid] + red[tid + 64] + red[tid + 128] + red[tid + 192]));
}

// ===================== shared node kernels ===================================
__global__ __launch_bounds__(256) void nodeA2_kernel(
    const float* __restrict__ x, const float* __restrict__ agg1,
    float* __restrict__ tbuf, const float* __restrict__ w1,
    const float* __restrict__ b1, const float* __restrict__ eps_p,
    float* __restrict__ stats) {
  __shared__ float red[256];
  int tid = threadIdx.x;
  int c = tid & 63, nl = tid >> 6;
  float wa = w1[c], wb = w1[64 + c], bc = b1[c];
  float ep = 1.0f + *eps_p;
  float s = 0.f, ss = 0.f;
  for (int n0 = blockIdx.x * 4; n0 < NN; n0 += gridDim.x * 4) {
    int n = n0 + nl;
    if (n < NN) {
      float h0 = ep * x[n * 2 + 0] + agg1[n * 2 + 0];
      float h1 = ep * x[n * 2 + 1] + agg1[n * 2 + 1];
      float t = fmaf(h1, wb, fmaf(h0, wa, bc));
      tbuf[n * 64 + c] = t;
      s += t;
      ss += t * t;
    }
  }
  double* dsum = (double*)stats;
  red[tid] = s;
  __syncthreads();
  if (tid < 64) unsafeAtomicAdd(&dsum[tid], (double)(red[tid] + red[tid + 64] + red[tid + 128] + red[tid + 192]));
  __syncthreads();
  red[tid] = ss;
  __syncthreads();
  if (tid < 64) unsafeAtomicAdd(&dsum[64 + tid], (double)(red[tid] + red[tid + 64] + red[tid + 128] + red[tid + 192]));
}

// --- node B with fused BN finalize: u=relu(BN(t)); out=relu(u@w2+b2)
// --- optionally emits fp16 copy of out (for next layer's gathers)
__global__ __launch_bounds__(256) void nodeB_kernel(
    const float* __restrict__ tin, float* __restrict__ outb,
    const float* __restrict__ w2, const float* __restrict__ b2,
    const float* __restrict__ stats, const float* __restrict__ g,
    const float* __restrict__ bt, unsigned short* __restrict__ xh) {
  __shared__ float wl[64 * 64];
  __shared__ float ubuf[4][64];
  __shared__ float scsh[128];
  int tid = threadIdx.x;
  int c = tid & 63, nl = tid >> 6;
  for (int i = tid; i < 64 * 64; i += 256) wl[i] = w2[i];
  if (tid < 64) {
    const double* ds = (const double*)stats;
    double m = ds[tid] / (double)NN;
    double v = ds[64 + tid] / (double)NN - m * m;
    float sc = g[tid] * (float)(1.0 / sqrt(v + 1e-5));
    scsh[tid] = sc;
    scsh[64 + tid] = bt[tid] - (float)m * sc;
  }
  float bc = b2[c];
  __syncthreads();
  float scale = scsh[c], shift = scsh[64 + c];
  for (int n0 = blockIdx.x * 4; n0 < NN; n0 += gridDim.x * 4) {
    int n = n0 + nl;
    bool valid = n < NN;
    float u = 0.f;
    if (valid) {
      float t = tin[n * 64 + c];
      u = fmaxf(fmaf(t, scale, shift), 0.f);
    }
    ubuf[nl][c] = u;
    __syncthreads();
    if (valid) {
      float o = bc;
#pragma unroll
      for (int k = 0; k < 64; k++) o = fmaf(ubuf[nl][k], wl[k * 64 + c], o);
      o = fmaxf(o, 0.f);
      outb[n * 64 + c] = o;
      if (xh) xh[n * 64 + c] = f1h(o);
    }
    __syncthreads();
  }
}

__global__ __launch_bounds__(256) void final_kernel(
    const float* __restrict__ xin, const float* __restrict__ regw,
    const float* __restrict__ regb, const float* __restrict__ endw,
    const float* __restrict__ endb, float* __restrict__ out) {
  __shared__ float wl[64 * 128];
  __shared__ float eb[256];
  int tid = threadIdx.x;
  int node = blockIdx.x * 256 + tid;
  bool valid = node < NN;
  float xr[64];
  if (valid) {
    const float4* xp = (const float4*)(xin + node * 64);
#pragma unroll
    for (int k4 = 0; k4 < 16; k4++) {
      float4 v = xp[k4];
      xr[k4 * 4 + 0] = v.x; xr[k4 * 4 + 1] = v.y;
      xr[k4 * 4 + 2] = v.z; xr[k4 * 4 + 3] = v.w;
    }
  }
  float y = 0.f;
  for (int ch = 0; ch < 4; ch++) {
    int j0 = ch * 125;
    __syncthreads();
    for (int idx = tid; idx < 64 * 125; idx += 256) {
      int k = idx / 125;
      int jl = idx - k * 125;
      wl[k * 128 + jl] = regw[k * 500 + j0 + jl];
    }
    if (tid < 125) { eb[tid] = regb[j0 + tid]; eb[128 + tid] = endw[j0 + tid]; }
    __syncthreads();
    if (valid) {
      int jl = 0;
      for (; jl + 4 <= 125; jl += 4) {
        float t0 = eb[jl], t1 = eb[jl + 1], t2 = eb[jl + 2], t3 = eb[jl + 3];
#pragma unroll
        for (int k = 0; k < 64; k++) {
          float4 w4 = *(const float4*)&wl[k * 128 + jl];
          float xv = xr[k];
          t0 = fmaf(xv, w4.x, t0);
          t1 = fmaf(xv, w4.y, t1);
          t2 = fmaf(xv, w4.z, t2);
          t3 = fmaf(xv, w4.w, t3);
        }
        t0 = t0 >= 0.f ? t0 : 0.01f * t0;
        t1 = t1 >= 0.f ? t1 : 0.01f * t1;
        t2 = t2 >= 0.f ? t2 : 0.01f * t2;
        t3 = t3 >= 0.f ? t3 : 0.01f * t3;
        y += t0 * eb[128 + jl] + t1 * eb[128 + jl + 1] + t2 * eb[128 + jl + 2] + t3 * eb[128 + jl + 3];
      }
      {
        float t = eb[124];
#pragma unroll
        for (int k = 0; k < 64; k++) t = fmaf(xr[k], wl[k * 128 + 124], t);
        t = t >= 0.f ? t : 0.01f * t;
        y += t * eb[128 + 124];
      }
    }
  }
  if (valid) out[node] = y + endb[0];
}

extern "C" void kernel_launch(void* const* d_in, const int* in_sizes, int n_in,
                              void* d_out, int out_size, void* d_ws, size_t ws_size,
                              hipStream_t stream) {
  const float* x    = (const float*)d_in[0];
  const float* ea   = (const float*)d_in[1];
  const int*   ei   = (const int*)d_in[2];
  const float* eps1 = (const float*)d_in[4];
  const float* el1w = (const float*)d_in[5];
  const float* el1b = (const float*)d_in[6];
  const float* n1w1 = (const float*)d_in[7];
  const float* n1b1 = (const float*)d_in[8];
  const float* n1g  = (const float*)d_in[9];
  const float* n1bt = (const float*)d_in[10];
  const float* n1w2 = (const float*)d_in[11];
  const float* n1b2 = (const float*)d_in[12];
  const float* eps2 = (const float*)d_in[13];
  const float* el2w = (const float*)d_in[14];
  const float* el2b = (const float*)d_in[15];
  const float* n2w1 = (const float*)d_in[16];
  const float* n2b1 = (const float*)d_in[17];
  const float* n2g  = (const float*)d_in[18];
  const float* n2bt = (const float*)d_in[19];
  const float* n2w2 = (const float*)d_in[20];
  const float* n2b2 = (const float*)d_in[21];
  const float* regw = (const float*)d_in[22];
  const float* regb = (const float*)d_in[23];
  const float* endw = (const float*)d_in[24];
  const float* endb = (const float*)d_in[25];
  const int* srcp = ei;
  const int* dstp = ei + NE;

  // ---- tier-A layout (float offsets) ----
  const size_t o_stats  = 0;          // 768 floats = 3 layers × 128 doubles
  const size_t o_cnt    = 768;        // NN ints (contiguous w/ stats: one memset)
  const size_t o_rowptr = 100768;     // NN+1 ints
  const size_t o_buf0   = 200832;     // N*64 floats; msg1 [E]float2 pre-layer-2
  const size_t o_buf1   = 6600832;    // N*64 floats
  const size_t o_xh     = 13000832;   // N*64 fp16 (= 3.2M floats)
  const size_t o_agg1   = 16200832;   // N*2 floats
  const size_t o_edat   = 16400832;   // packed: E uint4 | slim: E ints
  const size_t o_srcs   = 29200832;   // E ints (packed tier)
  const size_t needA2 = (o_srcs + (size_t)NE) * 4;  // ~129.6 MB
  const size_t needA1 = (o_edat + (size_t)NE) * 4;  // ~78.4 MB
  const size_t needB  = (2 * 6600000 + 384) * 4;    // ~52.8 MB

  float* wsf = (float*)d_ws;

  if (ws_size >= needA1) {
    const bool packed = ws_size >= needA2;
    float* stats0 = wsf + o_stats;        // layer 1
    float* stats1 = wsf + o_stats + 256;  // layer 2
    float* stats2 = wsf + o_stats + 512;  // layer 3
    int* cnt     = (int*)(wsf + o_cnt);
    int* rowptr  = (int*)(wsf + o_rowptr);
    float* buf0  = wsf + o_buf0;
    float* buf1  = wsf + o_buf1;
    unsigned short* xh = (unsigned short*)(wsf + o_xh);
    float* agg1  = wsf + o_agg1;
    uint4* erec  = (uint4*)(wsf + o_edat);
    int* esrc    = (int*)(wsf + o_srcs);
    float* msg1  = buf0;  // [E]float2 == N*64 floats exactly; free until layer 2

    // ---- one memset covers stats(3 layers) + cnt ----
    hipMemsetAsync(wsf, 0, (768 + NN) * sizeof(float), stream);

    // ---- CSR build (once, shared by all 3 layers) ----
    count_kernel<<<4096, 256, 0, stream>>>(dstp, cnt);
    scan_kernel<<<1, 1024, 0, stream>>>(cnt, rowptr, cnt);
    if (packed)
      scatter2h_kernel<<<4096, 256, 0, stream>>>(srcp, dstp, ea, cnt, erec, esrc,
                                                 x, el1w, el1b, msg1);
    else
      scatter1_kernel<<<4096, 256, 0, stream>>>(dstp, cnt, (int*)(wsf + o_edat));

    // ---- layer 1 ----
    if (packed)
      l1sum_kernel<<<391, 256, 0, stream>>>(rowptr, msg1, agg1);
    else
      l1agg_kernel<<<391, 256, 0, stream>>>(rowptr, (const int*)(wsf + o_edat),
                                            srcp, ea, x, el1w, el1b, agg1);
    nodeA2_kernel<<<2048, 256, 0, stream>>>(x, agg1, buf1, n1w1, n1b1, eps1, stats0);
    nodeB_kernel<<<2048, 256, 0, stream>>>(buf1, buf1, n1w2, n1b2, stats0,
                                           n1g, n1bt, packed ? xh : nullptr);

    // ---- layers 2,3 (shared weights) ----
    if (packed) {
      gine64h_kernel<<<4096, 256, 0, stream>>>(rowptr, erec, esrc, buf1, xh,
                                               el2w, el2b, n2w1, n2b1, eps2,
                                               buf0, stats1);
      nodeB_kernel<<<2048, 256, 0, stream>>>(buf0, buf0, n2w2, n2b2, stats1,
                                             n2g, n2bt, xh);
      gine64h_kernel<<<4096, 256, 0, stream>>>(rowptr, erec, esrc, buf0, xh,
                                               el2w, el2b, n2w1, n2b1, eps2,
                                               buf1, stats2);
      nodeB_kernel<<<2048, 256, 0, stream>>>(buf1, buf1, n2w2, n2b2, stats2,
                                             n2g, n2bt, nullptr);
      final_kernel<<<(NN + 255) / 256, 256, 0, stream>>>(buf1, regw, regb, endw,
                                                         endb, (float*)d_out);
    } else {
      float* cur = buf1;
      float* wrk = buf0;
      float* sl[2] = {stats1, stats2};
      for (int l = 0; l < 2; l++) {
        gine64s_kernel<<<4096, 256, 0, stream>>>(rowptr, (const int*)(wsf + o_edat),
                                                 srcp, ea, cur, el2w, el2b, n2w1,
                                                 n2b1, eps2, wrk, sl[l]);
        nodeB_kernel<<<2048, 256, 0, stream>>>(wrk, wrk, n2w2, n2b2, sl[l],
                                               n2g, n2bt, nullptr);
        float* tmp = cur; cur = wrk; wrk = tmp;
      }
      final_kernel<<<(NN + 255) / 256, 256, 0, stream>>>(cur, regw, regb, endw,
                                                         endb, (float*)d_out);
    }
    return;
  }

  // ================= fallback tier B (round-1 proven path) =================
  if (ws_size < needB) return;
  const size_t BUF = 6600000;
  float* buf0 = (float*)d_ws;
  float* buf1 = buf0 + BUF;
  float* stats = buf1 + BUF;

  float* t1 = buf1;
  float* agg1 = buf1 + NN * 64;
  hipMemsetAsync(agg1, 0, NN * 2 * sizeof(float), stream);
  hipMemsetAsync(stats, 0, 128 * sizeof(double), stream);
  edge1_kernel<<<2048, 256, 0, stream>>>(x, ea, srcp, dstp, el1w, el1b, agg1);
  nodeA2_kernel<<<2048, 256, 0, stream>>>(x, agg1, t1, n1w1, n1b1, eps1, stats);
  nodeB_kernel<<<2048, 256, 0, stream>>>(t1, buf1, n1w2, n1b2, stats, n1g, n1bt,
                                         nullptr);

  float* cur = buf1;
  float* wrk = buf0;
  for (int l = 0; l < 2; l++) {
    hipMemsetAsync(wrk, 0, NN * 64 * sizeof(float), stream);
    hipMemsetAsync(stats, 0, 128 * sizeof(double), stream);
    edge64_kernel<<<2048, 256, 0, stream>>>(cur, ea, srcp, dstp, el2w, el2b, wrk);
    nodeA64_kernel<<<2048, 256, 0, stream>>>(cur, wrk, n2w1, n2b1, eps2, stats);
    nodeB_kernel<<<2048, 256, 0, stream>>>(wrk, wrk, n2w2, n2b2, stats, n2g, n2bt,
                                           nullptr);
    float* tmp = cur; cur = wrk; wrk = tmp;
  }

  final_kernel<<<(NN + 255) / 256, 256, 0, stream>>>(cur, regw, regb, endw, endb,
                                                     (float*)d_out);
}